// Round 6
// baseline (12355.109 us; speedup 1.0000x reference)
//
#include <hip/hip_runtime.h>
#include <math.h>

#define NR 8192      // NA == NT
#define DIM 256
#define NBLK 512     // fused-kernel blocks == column-partial chunks
#define CROWS 16     // rows per chunk
// 10 * log2(e): converts distances directly into base-2 log domain
#define SCALE2 14.426950408889634f

// v_exp_f32 / v_log_f32 are base-2 natively — use them raw
__device__ __forceinline__ float fexp2(float x) {
#if __has_builtin(__builtin_amdgcn_exp2f)
    return __builtin_amdgcn_exp2f(x);
#else
    return exp2f(x);
#endif
}
__device__ __forceinline__ float flog2(float x) {
#if __has_builtin(__builtin_amdgcn_logf)
    return __builtin_amdgcn_logf(x);
#else
    return log2f(x);
#endif
}

// base-2 online LSE combine
__device__ __forceinline__ void lse_comb2(float& m, float& s, float mo, float so) {
    float nm = fmaxf(m, mo);
    s = s * fexp2(m - nm) + so * fexp2(mo - nm);
    m = nm;
}

// grouped-4 online LSE update (1 tree-max + 1 correction exp per 4 values)
__device__ __forceinline__ void lse_upd4(float& m, float& s,
                                         float v0, float v1, float v2, float v3) {
    float m4 = fmaxf(fmaxf(v0, v1), fmaxf(v2, v3));
    float nm = fmaxf(m, m4);
    float e = fexp2(v0 - nm) + fexp2(v1 - nm) + fexp2(v2 - nm) + fexp2(v3 - nm);
    s = fmaf(s, fexp2(m - nm), e);
    m = nm;
}

// single-value online LSE update
__device__ __forceinline__ void lse_upd1(float& m, float& s, float v) {
    float nm = fmaxf(m, v);
    s = s * fexp2(m - nm) + fexp2(v - nm);
    m = nm;
}

// ---------------- init ----------------
__global__ void init_zero(float* __restrict__ g) {
    int t = blockIdx.x * 256 + threadIdx.x;
    if (t < NR) g[t] = 0.0f;
}

// ---------------- out[M,DIM] = A[M,DIM] @ W[DIM,DIM] + bias ----------------
__global__ __launch_bounds__(256) void gemm_qk(const float* __restrict__ A,
                                               const float* __restrict__ W,
                                               const float* __restrict__ bias,
                                               float* __restrict__ out) {
    __shared__ float As[16][68];
    __shared__ float Ws[16][68];
    const int t  = threadIdx.x;
    const int r0 = blockIdx.x * 64;
    const int c0 = blockIdx.y * 64;
    const int ty = t >> 4, tx = t & 15;
    const int arow = t >> 2;
    const int ak   = (t & 3) * 4;
    const int wrow = t >> 4;
    const int wcol = (t & 15) * 4;
    float acc[4][4] = {};
    for (int k0 = 0; k0 < DIM; k0 += 16) {
        float4 av = *(const float4*)(A + (size_t)(r0 + arow) * DIM + k0 + ak);
        float4 wv = *(const float4*)(W + (size_t)(k0 + wrow) * DIM + c0 + wcol);
        __syncthreads();
        As[ak + 0][arow] = av.x; As[ak + 1][arow] = av.y;
        As[ak + 2][arow] = av.z; As[ak + 3][arow] = av.w;
        *(float4*)&Ws[wrow][wcol] = wv;
        __syncthreads();
#pragma unroll
        for (int kk = 0; kk < 16; ++kk) {
            float4 a = *(const float4*)&As[kk][ty * 4];
            float4 b = *(const float4*)&Ws[kk][tx * 4];
            float aa[4] = {a.x, a.y, a.z, a.w};
            float bb[4] = {b.x, b.y, b.z, b.w};
#pragma unroll
            for (int i = 0; i < 4; ++i)
#pragma unroll
                for (int j = 0; j < 4; ++j)
                    acc[i][j] = fmaf(aa[i], bb[j], acc[i][j]);
        }
    }
#pragma unroll
    for (int i = 0; i < 4; ++i) {
        float4 o;
        o.x = acc[i][0] + bias[c0 + tx * 4 + 0];
        o.y = acc[i][1] + bias[c0 + tx * 4 + 1];
        o.z = acc[i][2] + bias[c0 + tx * 4 + 2];
        o.w = acc[i][3] + bias[c0 + tx * 4 + 3];
        *(float4*)(out + (size_t)(r0 + ty * 4 + i) * DIM + c0 + tx * 4) = o;
    }
}

// ---------------- row squared norms ----------------
__global__ __launch_bounds__(64) void row_norm(const float* __restrict__ x,
                                               float* __restrict__ out) {
    const int row = blockIdx.x, lane = threadIdx.x;
    float4 v = *(const float4*)(x + (size_t)row * DIM + lane * 4);
    float s = v.x * v.x + v.y * v.y + v.z * v.z + v.w * v.w;
#pragma unroll
    for (int off = 32; off > 0; off >>= 1) s += __shfl_xor(s, off);
    if (lane == 0) out[row] = s;
}

// ---------------- MLP logits: relu(A@W1+b1)@W2 + b2 ----------------
__global__ __launch_bounds__(128) void mlp_logits(const float* __restrict__ A,
                                                  const float* __restrict__ W1,
                                                  const float* __restrict__ b1,
                                                  const float* __restrict__ W2,
                                                  const float* __restrict__ b2,
                                                  float* __restrict__ logits) {
    __shared__ float ar[DIM];
    __shared__ float red[2];
    const int t = threadIdx.x;
    const int row = blockIdx.x;
    *(float2*)&ar[t * 2] = *(const float2*)(A + (size_t)row * DIM + t * 2);
    __syncthreads();
    float h = b1[t];
#pragma unroll 8
    for (int kk = 0; kk < DIM; ++kk) h = fmaf(ar[kk], W1[kk * 128 + t], h);
    float val = fmaxf(h, 0.0f) * W2[t];
#pragma unroll
    for (int off = 32; off > 0; off >>= 1) val += __shfl_xor(val, off);
    if ((t & 63) == 0) red[t >> 6] = val;
    __syncthreads();
    if (t == 0) logits[row] = red[0] + red[1] + b2[0];
}

// ---------------- softmax over 8192 logits -> log2(b + 1e-20) ----------------
__global__ __launch_bounds__(1024) void softmax_logb(const float* __restrict__ logits,
                                                     float* __restrict__ logb2) {
    __shared__ float redm[16], reds[16];
    const int t = threadIdx.x;
    float l[8];
    float m = -INFINITY;
#pragma unroll
    for (int i = 0; i < 8; ++i) { l[i] = logits[i * 1024 + t]; m = fmaxf(m, l[i]); }
#pragma unroll
    for (int off = 32; off > 0; off >>= 1) m = fmaxf(m, __shfl_xor(m, off));
    if ((t & 63) == 0) redm[t >> 6] = m;
    __syncthreads();
    if (t < 64) {
        float v = (t < 16) ? redm[t] : -INFINITY;
#pragma unroll
        for (int off = 8; off > 0; off >>= 1) v = fmaxf(v, __shfl_xor(v, off));
        if (t == 0) redm[0] = v;
    }
    __syncthreads();
    m = redm[0];
    float s = 0.0f;
#pragma unroll
    for (int i = 0; i < 8; ++i) s += __expf(l[i] - m);
#pragma unroll
    for (int off = 32; off > 0; off >>= 1) s += __shfl_xor(s, off);
    if ((t & 63) == 0) reds[t >> 6] = s;
    __syncthreads();
    if (t < 64) {
        float v = (t < 16) ? reds[t] : 0.0f;
#pragma unroll
        for (int off = 8; off > 0; off >>= 1) v += __shfl_xor(v, off);
        if (t == 0) reds[0] = v;
    }
    __syncthreads();
    s = reds[0];
    float invs = 1.0f / s;
#pragma unroll
    for (int i = 0; i < 8; ++i)
        logb2[i * 1024 + t] = log2f(__expf(l[i] - m) * invs + 1e-20f);
}

// ---------------- S[i][j] = log2e*10*(qn_i + kn_j - 2*q_i.k_j) ----------------
__global__ __launch_bounds__(256) void dist_kernel(const float* __restrict__ q,
                                                   const float* __restrict__ k,
                                                   const float* __restrict__ qn,
                                                   const float* __restrict__ kn,
                                                   float* __restrict__ S) {
    __shared__ float Qs[16][132];
    __shared__ float Ks[16][132];
    const int t  = threadIdx.x;
    const int r0 = blockIdx.y * 128;
    const int c0 = blockIdx.x * 128;
    const int lrow = t >> 1;
    const int lk   = (t & 1) * 8;
    const int wv   = t >> 6;
    const int lane = t & 63;
    const int ty8 = (wv >> 1) * 8 + (lane >> 3);
    const int tx8 = (wv & 1) * 8 + (lane & 7);
    float acc[8][8] = {};
    for (int k0 = 0; k0 < DIM; k0 += 16) {
        float4 qa = *(const float4*)(q + (size_t)(r0 + lrow) * DIM + k0 + lk);
        float4 qb = *(const float4*)(q + (size_t)(r0 + lrow) * DIM + k0 + lk + 4);
        float4 ka = *(const float4*)(k + (size_t)(c0 + lrow) * DIM + k0 + lk);
        float4 kb = *(const float4*)(k + (size_t)(c0 + lrow) * DIM + k0 + lk + 4);
        __syncthreads();
        Qs[lk + 0][lrow] = qa.x; Qs[lk + 1][lrow] = qa.y;
        Qs[lk + 2][lrow] = qa.z; Qs[lk + 3][lrow] = qa.w;
        Qs[lk + 4][lrow] = qb.x; Qs[lk + 5][lrow] = qb.y;
        Qs[lk + 6][lrow] = qb.z; Qs[lk + 7][lrow] = qb.w;
        Ks[lk + 0][lrow] = ka.x; Ks[lk + 1][lrow] = ka.y;
        Ks[lk + 2][lrow] = ka.z; Ks[lk + 3][lrow] = ka.w;
        Ks[lk + 4][lrow] = kb.x; Ks[lk + 5][lrow] = kb.y;
        Ks[lk + 6][lrow] = kb.z; Ks[lk + 7][lrow] = kb.w;
        __syncthreads();
#pragma unroll
        for (int kk = 0; kk < 16; ++kk) {
            float4 a0 = *(const float4*)&Qs[kk][ty8 * 8];
            float4 a1 = *(const float4*)&Qs[kk][ty8 * 8 + 4];
            float4 b0 = *(const float4*)&Ks[kk][tx8 * 8];
            float4 b1 = *(const float4*)&Ks[kk][tx8 * 8 + 4];
            float aa[8] = {a0.x, a0.y, a0.z, a0.w, a1.x, a1.y, a1.z, a1.w};
            float bb[8] = {b0.x, b0.y, b0.z, b0.w, b1.x, b1.y, b1.z, b1.w};
#pragma unroll
            for (int i = 0; i < 8; ++i)
#pragma unroll
                for (int j = 0; j < 8; ++j)
                    acc[i][j] = fmaf(aa[i], bb[j], acc[i][j]);
        }
    }
    float knv[8];
#pragma unroll
    for (int j = 0; j < 8; ++j) knv[j] = kn[c0 + tx8 * 8 + j];
#pragma unroll
    for (int i = 0; i < 8; ++i) {
        const int row = r0 + ty8 * 8 + i;
        const float qni = qn[row];
        float* outp = S + (size_t)row * NR + c0 + tx8 * 8;
        float4 o0, o1;
        o0.x = (qni + knv[0] - 2.0f * acc[i][0]) * SCALE2;
        o0.y = (qni + knv[1] - 2.0f * acc[i][1]) * SCALE2;
        o0.z = (qni + knv[2] - 2.0f * acc[i][2]) * SCALE2;
        o0.w = (qni + knv[3] - 2.0f * acc[i][3]) * SCALE2;
        o1.x = (qni + knv[4] - 2.0f * acc[i][4]) * SCALE2;
        o1.y = (qni + knv[5] - 2.0f * acc[i][5]) * SCALE2;
        o1.z = (qni + knv[6] - 2.0f * acc[i][6]) * SCALE2;
        o1.w = (qni + knv[7] - 2.0f * acc[i][7]) * SCALE2;
        *(float4*)outp = o0;
        *(float4*)(outp + 4) = o1;
    }
}

// ---------------- fused iteration: single-read row LSE + column partials ----------------
// 512 blocks x 512 threads, 16 rows per block, processed one row at a time.
// Thread t owns cols {j*2048 + 4t + c : j in 0..3, c in 0..3}. Each step, the
// thread's 16 row values serve BOTH the row-LSE (with +g, block-reduced -> f_i)
// AND the column accumulators (with +f_i) — S is read exactly once per iteration,
// straight into VGPRs. Row i+1 is prefetched (VGPR double buffer) while row i
// goes through the two reduction barriers, keeping HBM busy.
__global__ __launch_bounds__(512, 4) void iter_fused(const float* __restrict__ S,
                                                     const float* __restrict__ g,
                                                     const float* __restrict__ logb2,
                                                     float* __restrict__ f,
                                                     float2* __restrict__ pms) {
    __shared__ float redm[8], reds[8];
    __shared__ float fsh;
    const int t = threadIdx.x;
    const int wv = t >> 6, lane = t & 63;
    const int chunk = blockIdx.x;
    const int r0 = chunk * CROWS;
    const int coff = t * 4;

    // g slice for this thread's columns (constant across the kernel)
    float4 gv[4];
#pragma unroll
    for (int j = 0; j < 4; ++j)
        gv[j] = *(const float4*)(g + j * 2048 + coff);

    // column accumulators
    float cm[4][4], cs[4][4];
#pragma unroll
    for (int j = 0; j < 4; ++j)
#pragma unroll
        for (int c = 0; c < 4; ++c) { cm[j][c] = -INFINITY; cs[j][c] = 0.0f; }

    // prime row 0
    float4 vb[2][4];
    {
        const float* Sr = S + (size_t)r0 * NR;
#pragma unroll
        for (int j = 0; j < 4; ++j)
            vb[0][j] = *(const float4*)(Sr + j * 2048 + coff);
    }

#pragma unroll
    for (int i = 0; i < CROWS; ++i) {
        const int cur = i & 1, nxt = cur ^ 1;
        // prefetch next row (overlaps the two barriers below)
        if (i + 1 < CROWS) {
            const float* Sn = S + (size_t)(r0 + i + 1) * NR;
#pragma unroll
            for (int j = 0; j < 4; ++j)
                vb[nxt][j] = *(const float4*)(Sn + j * 2048 + coff);
        }
        // row-LSE over this thread's 16 cols (values + g)
        float m = -INFINITY, s = 0.0f;
#pragma unroll
        for (int j = 0; j < 4; ++j) {
            float4 v = vb[cur][j];
            lse_upd4(m, s, v.x + gv[j].x, v.y + gv[j].y, v.z + gv[j].z, v.w + gv[j].w);
        }
        // wave reduce
#pragma unroll
        for (int off = 32; off > 0; off >>= 1) {
            float mo = __shfl_xor(m, off);
            float so = __shfl_xor(s, off);
            lse_comb2(m, s, mo, so);
        }
        if (lane == 0) { redm[wv] = m; reds[wv] = s; }
        __syncthreads();
        if (t == 0) {
            float mm = redm[0], ss = reds[0];
#pragma unroll
            for (int w = 1; w < 8; ++w) lse_comb2(mm, ss, redm[w], reds[w]);
            float fv = logb2[r0 + i] - (mm + flog2(ss));
            fsh = fv;
            f[r0 + i] = fv;
        }
        __syncthreads();
        const float fi = fsh;
        // column accumulate from the SAME registers (no second read of S)
#pragma unroll
        for (int j = 0; j < 4; ++j) {
            float4 v = vb[cur][j];
            lse_upd1(cm[j][0], cs[j][0], v.x + fi);
            lse_upd1(cm[j][1], cs[j][1], v.y + fi);
            lse_upd1(cm[j][2], cs[j][2], v.z + fi);
            lse_upd1(cm[j][3], cs[j][3], v.w + fi);
        }
    }
    // write column partials for this chunk
#pragma unroll
    for (int j = 0; j < 4; ++j) {
        float2* o = pms + (size_t)chunk * NR + j * 2048 + coff;
        o[0] = make_float2(cm[j][0], cs[j][0]);
        o[1] = make_float2(cm[j][1], cs[j][1]);
        o[2] = make_float2(cm[j][2], cs[j][2]);
        o[3] = make_float2(cm[j][3], cs[j][3]);
    }
}

// ---------------- combine partials -> g ----------------
__global__ __launch_bounds__(256) void col_combine(const float2* __restrict__ pms,
                                                   float* __restrict__ g,
                                                   float log_a2) {
    const int col = blockIdx.x * 256 + threadIdx.x;
    float m = -INFINITY, s = 0.0f;
#pragma unroll 8
    for (int ch = 0; ch < NBLK; ++ch) {
        float2 p = pms[(size_t)ch * NR + col];
        lse_comb2(m, s, p.x, p.y);
    }
    g[col] = log_a2 - (m + flog2(s));
}

// ---------------- T = exp2(f + S + g), in place; global sum == 1 analytically ----------------
// note: no __restrict__ on S/out — they alias (in-place)
__global__ __launch_bounds__(256) void write_pass(const float* S,
                                                  const float* __restrict__ f,
                                                  const float* __restrict__ g,
                                                  float* out) {
    const int wv = threadIdx.x >> 6, lane = threadIdx.x & 63;
    const int row = blockIdx.x * 4 + wv;
    const float fi = f[row];
    const float4* Sr = (const float4*)(S + (size_t)row * NR);
    const float4* gr = (const float4*)g;
    float4* Or = (float4*)(out + (size_t)row * NR);
#pragma unroll 4
    for (int it = 0; it < NR / 256; ++it) {
        const int idx = it * 64 + lane;
        float4 sv = Sr[idx];
        float4 gv = gr[idx];
        float4 o;
        o.x = fexp2(fi + sv.x + gv.x);
        o.y = fexp2(fi + sv.y + gv.y);
        o.z = fexp2(fi + sv.z + gv.z);
        o.w = fexp2(fi + sv.w + gv.w);
        Or[idx] = o;
    }
}

extern "C" void kernel_launch(void* const* d_in, const int* in_sizes, int n_in,
                              void* d_out, int out_size, void* d_ws, size_t ws_size,
                              hipStream_t stream) {
    (void)in_sizes; (void)n_in; (void)out_size; (void)ws_size;
    const float* A  = (const float*)d_in[0];
    const float* Tk = (const float*)d_in[1];
    const float* Wq = (const float*)d_in[2];
    const float* bq = (const float*)d_in[3];
    const float* Wk = (const float*)d_in[4];
    const float* bk = (const float*)d_in[5];
    const float* W1 = (const float*)d_in[6];
    const float* b1 = (const float*)d_in[7];
    const float* W2 = (const float*)d_in[8];
    const float* b2 = (const float*)d_in[9];
    float* S  = (float*)d_out;           // 8192x8192 base-2 log_K lives in d_out
    float* ws = (float*)d_ws;
    float* qn     = ws; ws += NR;
    float* kn     = ws; ws += NR;
    float* logb2  = ws; ws += NR;
    float* logits = ws; ws += NR;
    float* f      = ws; ws += NR;
    float* g      = ws; ws += NR;
    float2* pms   = (float2*)ws;         // NBLK * NR float2 = 32 MB
    // q,k (8 MB each) overlay the pms region: dist phase completes before any
    // partial is written, and q/k are dead once dist_kernel finishes.
    float* q = (float*)pms;
    float* k = q + (size_t)NR * DIM;

    const float log_a2 = -13.0f; // log2(1/8192 + 1e-20)

    init_zero<<<32, 256, 0, stream>>>(g);
    gemm_qk<<<dim3(128, 4), 256, 0, stream>>>(A, Wq, bq, q);
    gemm_qk<<<dim3(128, 4), 256, 0, stream>>>(Tk, Wk, bk, k);
    row_norm<<<NR, 64, 0, stream>>>(q, qn);
    row_norm<<<NR, 64, 0, stream>>>(k, kn);
    mlp_logits<<<NR, 128, 0, stream>>>(A, W1, b1, W2, b2, logits);
    softmax_logb<<<1, 1024, 0, stream>>>(logits, logb2);
    dist_kernel<<<dim3(64, 64), 256, 0, stream>>>(q, k, qn, kn, S);
    for (int it = 0; it < 50; ++it) {
        iter_fused<<<NBLK, 512, 0, stream>>>(S, g, logb2, f, pms);
        col_combine<<<32, 256, 0, stream>>>(pms, g, log_a2);
    }
    write_pass<<<NR / 4, 256, 0, stream>>>(S, f, g, S);
}

// Round 7
// 4445.484 us; speedup vs baseline: 2.7792x; 2.7792x over previous
//
#include <hip/hip_runtime.h>
#include <math.h>

#define NR 8192      // NA == NT
#define DIM 256
#define NBLK 256     // fused-kernel blocks == column-partial chunks (1 per CU)
#define CROWS 32     // rows per chunk
#define NSUB 8       // sub-chunks per chunk (4 rows each)
// 10 * log2(e): converts distances directly into base-2 log domain
#define SCALE2 14.426950408889634f

// v_exp_f32 / v_log_f32 are base-2 natively — use them raw
__device__ __forceinline__ float fexp2(float x) {
#if __has_builtin(__builtin_amdgcn_exp2f)
    return __builtin_amdgcn_exp2f(x);
#else
    return exp2f(x);
#endif
}
__device__ __forceinline__ float flog2(float x) {
#if __has_builtin(__builtin_amdgcn_logf)
    return __builtin_amdgcn_logf(x);
#else
    return log2f(x);
#endif
}

// base-2 online LSE combine
__device__ __forceinline__ void lse_comb2(float& m, float& s, float mo, float so) {
    float nm = fmaxf(m, mo);
    s = s * fexp2(m - nm) + so * fexp2(mo - nm);
    m = nm;
}

// grouped-4 online LSE update (1 tree-max + 1 correction exp per 4 values)
__device__ __forceinline__ void lse_upd4(float& m, float& s,
                                         float v0, float v1, float v2, float v3) {
    float m4 = fmaxf(fmaxf(v0, v1), fmaxf(v2, v3));
    float nm = fmaxf(m, m4);
    float e = fexp2(v0 - nm) + fexp2(v1 - nm) + fexp2(v2 - nm) + fexp2(v3 - nm);
    s = fmaf(s, fexp2(m - nm), e);
    m = nm;
}

// ---------------- init ----------------
__global__ void init_zero(float* __restrict__ g) {
    int t = blockIdx.x * 256 + threadIdx.x;
    if (t < NR) g[t] = 0.0f;
}

// ---------------- out[M,DIM] = A[M,DIM] @ W[DIM,DIM] + bias ----------------
__global__ __launch_bounds__(256) void gemm_qk(const float* __restrict__ A,
                                               const float* __restrict__ W,
                                               const float* __restrict__ bias,
                                               float* __restrict__ out) {
    __shared__ float As[16][68];
    __shared__ float Ws[16][68];
    const int t  = threadIdx.x;
    const int r0 = blockIdx.x * 64;
    const int c0 = blockIdx.y * 64;
    const int ty = t >> 4, tx = t & 15;
    const int arow = t >> 2;
    const int ak   = (t & 3) * 4;
    const int wrow = t >> 4;
    const int wcol = (t & 15) * 4;
    float acc[4][4] = {};
    for (int k0 = 0; k0 < DIM; k0 += 16) {
        float4 av = *(const float4*)(A + (size_t)(r0 + arow) * DIM + k0 + ak);
        float4 wv = *(const float4*)(W + (size_t)(k0 + wrow) * DIM + c0 + wcol);
        __syncthreads();
        As[ak + 0][arow] = av.x; As[ak + 1][arow] = av.y;
        As[ak + 2][arow] = av.z; As[ak + 3][arow] = av.w;
        *(float4*)&Ws[wrow][wcol] = wv;
        __syncthreads();
#pragma unroll
        for (int kk = 0; kk < 16; ++kk) {
            float4 a = *(const float4*)&As[kk][ty * 4];
            float4 b = *(const float4*)&Ws[kk][tx * 4];
            float aa[4] = {a.x, a.y, a.z, a.w};
            float bb[4] = {b.x, b.y, b.z, b.w};
#pragma unroll
            for (int i = 0; i < 4; ++i)
#pragma unroll
                for (int j = 0; j < 4; ++j)
                    acc[i][j] = fmaf(aa[i], bb[j], acc[i][j]);
        }
    }
#pragma unroll
    for (int i = 0; i < 4; ++i) {
        float4 o;
        o.x = acc[i][0] + bias[c0 + tx * 4 + 0];
        o.y = acc[i][1] + bias[c0 + tx * 4 + 1];
        o.z = acc[i][2] + bias[c0 + tx * 4 + 2];
        o.w = acc[i][3] + bias[c0 + tx * 4 + 3];
        *(float4*)(out + (size_t)(r0 + ty * 4 + i) * DIM + c0 + tx * 4) = o;
    }
}

// ---------------- row squared norms ----------------
__global__ __launch_bounds__(64) void row_norm(const float* __restrict__ x,
                                               float* __restrict__ out) {
    const int row = blockIdx.x, lane = threadIdx.x;
    float4 v = *(const float4*)(x + (size_t)row * DIM + lane * 4);
    float s = v.x * v.x + v.y * v.y + v.z * v.z + v.w * v.w;
#pragma unroll
    for (int off = 32; off > 0; off >>= 1) s += __shfl_xor(s, off);
    if (lane == 0) out[row] = s;
}

// ---------------- MLP logits: relu(A@W1+b1)@W2 + b2 ----------------
__global__ __launch_bounds__(128) void mlp_logits(const float* __restrict__ A,
                                                  const float* __restrict__ W1,
                                                  const float* __restrict__ b1,
                                                  const float* __restrict__ W2,
                                                  const float* __restrict__ b2,
                                                  float* __restrict__ logits) {
    __shared__ float ar[DIM];
    __shared__ float red[2];
    const int t = threadIdx.x;
    const int row = blockIdx.x;
    *(float2*)&ar[t * 2] = *(const float2*)(A + (size_t)row * DIM + t * 2);
    __syncthreads();
    float h = b1[t];
#pragma unroll 8
    for (int kk = 0; kk < DIM; ++kk) h = fmaf(ar[kk], W1[kk * 128 + t], h);
    float val = fmaxf(h, 0.0f) * W2[t];
#pragma unroll
    for (int off = 32; off > 0; off >>= 1) val += __shfl_xor(val, off);
    if ((t & 63) == 0) red[t >> 6] = val;
    __syncthreads();
    if (t == 0) logits[row] = red[0] + red[1] + b2[0];
}

// ---------------- softmax over 8192 logits -> log2(b + 1e-20) ----------------
__global__ __launch_bounds__(1024) void softmax_logb(const float* __restrict__ logits,
                                                     float* __restrict__ logb2) {
    __shared__ float redm[16], reds[16];
    const int t = threadIdx.x;
    float l[8];
    float m = -INFINITY;
#pragma unroll
    for (int i = 0; i < 8; ++i) { l[i] = logits[i * 1024 + t]; m = fmaxf(m, l[i]); }
#pragma unroll
    for (int off = 32; off > 0; off >>= 1) m = fmaxf(m, __shfl_xor(m, off));
    if ((t & 63) == 0) redm[t >> 6] = m;
    __syncthreads();
    if (t < 64) {
        float v = (t < 16) ? redm[t] : -INFINITY;
#pragma unroll
        for (int off = 8; off > 0; off >>= 1) v = fmaxf(v, __shfl_xor(v, off));
        if (t == 0) redm[0] = v;
    }
    __syncthreads();
    m = redm[0];
    float s = 0.0f;
#pragma unroll
    for (int i = 0; i < 8; ++i) s += __expf(l[i] - m);
#pragma unroll
    for (int off = 32; off > 0; off >>= 1) s += __shfl_xor(s, off);
    if ((t & 63) == 0) reds[t >> 6] = s;
    __syncthreads();
    if (t < 64) {
        float v = (t < 16) ? reds[t] : 0.0f;
#pragma unroll
        for (int off = 8; off > 0; off >>= 1) v += __shfl_xor(v, off);
        if (t == 0) reds[0] = v;
    }
    __syncthreads();
    s = reds[0];
    float invs = 1.0f / s;
#pragma unroll
    for (int i = 0; i < 8; ++i)
        logb2[i * 1024 + t] = log2f(__expf(l[i] - m) * invs + 1e-20f);
}

// ---------------- S[i][j] = log2e*10*(qn_i + kn_j - 2*q_i.k_j) ----------------
__global__ __launch_bounds__(256) void dist_kernel(const float* __restrict__ q,
                                                   const float* __restrict__ k,
                                                   const float* __restrict__ qn,
                                                   const float* __restrict__ kn,
                                                   float* __restrict__ S) {
    __shared__ float Qs[16][132];
    __shared__ float Ks[16][132];
    const int t  = threadIdx.x;
    const int r0 = blockIdx.y * 128;
    const int c0 = blockIdx.x * 128;
    const int lrow = t >> 1;
    const int lk   = (t & 1) * 8;
    const int wv   = t >> 6;
    const int lane = t & 63;
    const int ty8 = (wv >> 1) * 8 + (lane >> 3);
    const int tx8 = (wv & 1) * 8 + (lane & 7);
    float acc[8][8] = {};
    for (int k0 = 0; k0 < DIM; k0 += 16) {
        float4 qa = *(const float4*)(q + (size_t)(r0 + lrow) * DIM + k0 + lk);
        float4 qb = *(const float4*)(q + (size_t)(r0 + lrow) * DIM + k0 + lk + 4);
        float4 ka = *(const float4*)(k + (size_t)(c0 + lrow) * DIM + k0 + lk);
        float4 kb = *(const float4*)(k + (size_t)(c0 + lrow) * DIM + k0 + lk + 4);
        __syncthreads();
        Qs[lk + 0][lrow] = qa.x; Qs[lk + 1][lrow] = qa.y;
        Qs[lk + 2][lrow] = qa.z; Qs[lk + 3][lrow] = qa.w;
        Qs[lk + 4][lrow] = qb.x; Qs[lk + 5][lrow] = qb.y;
        Qs[lk + 6][lrow] = qb.z; Qs[lk + 7][lrow] = qb.w;
        Ks[lk + 0][lrow] = ka.x; Ks[lk + 1][lrow] = ka.y;
        Ks[lk + 2][lrow] = ka.z; Ks[lk + 3][lrow] = ka.w;
        Ks[lk + 4][lrow] = kb.x; Ks[lk + 5][lrow] = kb.y;
        Ks[lk + 6][lrow] = kb.z; Ks[lk + 7][lrow] = kb.w;
        __syncthreads();
#pragma unroll
        for (int kk = 0; kk < 16; ++kk) {
            float4 a0 = *(const float4*)&Qs[kk][ty8 * 8];
            float4 a1 = *(const float4*)&Qs[kk][ty8 * 8 + 4];
            float4 b0 = *(const float4*)&Ks[kk][tx8 * 8];
            float4 b1 = *(const float4*)&Ks[kk][tx8 * 8 + 4];
            float aa[8] = {a0.x, a0.y, a0.z, a0.w, a1.x, a1.y, a1.z, a1.w};
            float bb[8] = {b0.x, b0.y, b0.z, b0.w, b1.x, b1.y, b1.z, b1.w};
#pragma unroll
            for (int i = 0; i < 8; ++i)
#pragma unroll
                for (int j = 0; j < 8; ++j)
                    acc[i][j] = fmaf(aa[i], bb[j], acc[i][j]);
        }
    }
    float knv[8];
#pragma unroll
    for (int j = 0; j < 8; ++j) knv[j] = kn[c0 + tx8 * 8 + j];
#pragma unroll
    for (int i = 0; i < 8; ++i) {
        const int row = r0 + ty8 * 8 + i;
        const float qni = qn[row];
        float* outp = S + (size_t)row * NR + c0 + tx8 * 8;
        float4 o0, o1;
        o0.x = (qni + knv[0] - 2.0f * acc[i][0]) * SCALE2;
        o0.y = (qni + knv[1] - 2.0f * acc[i][1]) * SCALE2;
        o0.z = (qni + knv[2] - 2.0f * acc[i][2]) * SCALE2;
        o0.w = (qni + knv[3] - 2.0f * acc[i][3]) * SCALE2;
        o1.x = (qni + knv[4] - 2.0f * acc[i][4]) * SCALE2;
        o1.y = (qni + knv[5] - 2.0f * acc[i][5]) * SCALE2;
        o1.z = (qni + knv[6] - 2.0f * acc[i][6]) * SCALE2;
        o1.w = (qni + knv[7] - 2.0f * acc[i][7]) * SCALE2;
        *(float4*)outp = o0;
        *(float4*)(outp + 4) = o1;
    }
}

// ---------------- fused iteration: row LSE + column partials, LDS-staged ----------------
// 256 blocks (1/CU) x 512 threads (8 waves), 32 rows per block, 4-row sub-chunks.
// Phase 1: 2 waves per row scan HBM once (16 KB/wave in flight between barriers),
// staging the scanned values into LDS (4 rows x 32 KB = 128 KB). Phase 2 reads the
// 4 rows back from LDS (not L2 — round 5's phase-2 re-read thrashed the 4 MB/XCD L2
// and went to HBM; LDS staging removes that 268 MB/iter of HBM traffic).
__global__ __launch_bounds__(512, 2) void iter_fused(const float* __restrict__ S,
                                                     const float* __restrict__ g,
                                                     const float* __restrict__ logb2,
                                                     float* __restrict__ f,
                                                     float2* __restrict__ pms) {
    __shared__ float Srow[4][NR];     // 128 KB staging
    __shared__ float redm[8], reds[8];
    const int t = threadIdx.x;
    const int wv = t >> 6, lane = t & 63;
    const int chunk = blockIdx.x;
    const int r0 = chunk * CROWS;
    const int rw   = wv >> 1;         // row (0..3) this wave scans
    const int half = wv & 1;          // which half of the row
    const int base = half * 4096;

    // column accumulators: thread t owns cols {j*2048 + t*4 + c}
    float cm[4][4], cs[4][4];
#pragma unroll
    for (int j = 0; j < 4; ++j)
#pragma unroll
        for (int c = 0; c < 4; ++c) { cm[j][c] = -INFINITY; cs[j][c] = 0.0f; }

    for (int sc = 0; sc < NSUB; ++sc) {
        // ---- phase 1: scan row (r0 + sc*4 + rw), half `half`, stage to LDS ----
        const int row = r0 + sc * 4 + rw;
        const float* Sr = S + (size_t)row * NR + base;
        const float* gp = g + base;
        float m = -INFINITY, s = 0.0f;
#pragma unroll
        for (int it = 0; it < 16; ++it) {
            const int off = it * 256 + lane * 4;
            float4 sv = *(const float4*)(Sr + off);
            float4 gv = *(const float4*)(gp + off);
            *(float4*)&Srow[rw][base + off] = sv;
            lse_upd4(m, s, sv.x + gv.x, sv.y + gv.y, sv.z + gv.z, sv.w + gv.w);
        }
#pragma unroll
        for (int off = 32; off > 0; off >>= 1) {
            float mo = __shfl_xor(m, off);
            float so = __shfl_xor(s, off);
            lse_comb2(m, s, mo, so);
        }
        if (lane == 0) { redm[wv] = m; reds[wv] = s; }
        __syncthreads();   // LDS staging + red arrays visible

        // ---- all threads: combine the two half-row partials -> f0..f3 ----
        float fr[4];
#pragma unroll
        for (int r = 0; r < 4; ++r) {
            float mm = redm[2 * r], ss = reds[2 * r];
            lse_comb2(mm, ss, redm[2 * r + 1], reds[2 * r + 1]);
            fr[r] = logb2[r0 + sc * 4 + r] - (mm + flog2(ss));
        }
        if (t < 4) f[r0 + sc * 4 + t] = fr[t];

        // ---- phase 2: column partial-LSE over the 4 staged rows (LDS reads) ----
#pragma unroll
        for (int j = 0; j < 4; ++j) {
            const int c = j * 2048 + t * 4;
            float4 a = *(const float4*)&Srow[0][c];
            float4 b = *(const float4*)&Srow[1][c];
            float4 cc = *(const float4*)&Srow[2][c];
            float4 d = *(const float4*)&Srow[3][c];
            lse_upd4(cm[j][0], cs[j][0], a.x + fr[0], b.x + fr[1], cc.x + fr[2], d.x + fr[3]);
            lse_upd4(cm[j][1], cs[j][1], a.y + fr[0], b.y + fr[1], cc.y + fr[2], d.y + fr[3]);
            lse_upd4(cm[j][2], cs[j][2], a.z + fr[0], b.z + fr[1], cc.z + fr[2], d.z + fr[3]);
            lse_upd4(cm[j][3], cs[j][3], a.w + fr[0], b.w + fr[1], cc.w + fr[2], d.w + fr[3]);
        }
        __syncthreads();   // protect Srow before next sub-chunk overwrites it
    }
    // write column partials for this chunk
#pragma unroll
    for (int j = 0; j < 4; ++j) {
        float2* o = pms + (size_t)chunk * NR + j * 2048 + t * 4;
        o[0] = make_float2(cm[j][0], cs[j][0]);
        o[1] = make_float2(cm[j][1], cs[j][1]);
        o[2] = make_float2(cm[j][2], cs[j][2]);
        o[3] = make_float2(cm[j][3], cs[j][3]);
    }
}

// ---------------- combine partials -> g ----------------
__global__ __launch_bounds__(256) void col_combine(const float2* __restrict__ pms,
                                                   float* __restrict__ g,
                                                   float log_a2) {
    const int col = blockIdx.x * 256 + threadIdx.x;
    float m = -INFINITY, s = 0.0f;
#pragma unroll 8
    for (int ch = 0; ch < NBLK; ++ch) {
        float2 p = pms[(size_t)ch * NR + col];
        lse_comb2(m, s, p.x, p.y);
    }
    g[col] = log_a2 - (m + flog2(s));
}

// ---------------- T = exp2(f + S + g), in place; global sum == 1 analytically ----------------
// note: no __restrict__ on S/out — they alias (in-place)
__global__ __launch_bounds__(256) void write_pass(const float* S,
                                                  const float* __restrict__ f,
                                                  const float* __restrict__ g,
                                                  float* out) {
    const int wv = threadIdx.x >> 6, lane = threadIdx.x & 63;
    const int row = blockIdx.x * 4 + wv;
    const float fi = f[row];
    const float4* Sr = (const float4*)(S + (size_t)row * NR);
    const float4* gr = (const float4*)g;
    float4* Or = (float4*)(out + (size_t)row * NR);
#pragma unroll 4
    for (int it = 0; it < NR / 256; ++it) {
        const int idx = it * 64 + lane;
        float4 sv = Sr[idx];
        float4 gv = gr[idx];
        float4 o;
        o.x = fexp2(fi + sv.x + gv.x);
        o.y = fexp2(fi + sv.y + gv.y);
        o.z = fexp2(fi + sv.z + gv.z);
        o.w = fexp2(fi + sv.w + gv.w);
        Or[idx] = o;
    }
}

extern "C" void kernel_launch(void* const* d_in, const int* in_sizes, int n_in,
                              void* d_out, int out_size, void* d_ws, size_t ws_size,
                              hipStream_t stream) {
    (void)in_sizes; (void)n_in; (void)out_size; (void)ws_size;
    const float* A  = (const float*)d_in[0];
    const float* Tk = (const float*)d_in[1];
    const float* Wq = (const float*)d_in[2];
    const float* bq = (const float*)d_in[3];
    const float* Wk = (const float*)d_in[4];
    const float* bk = (const float*)d_in[5];
    const float* W1 = (const float*)d_in[6];
    const float* b1 = (const float*)d_in[7];
    const float* W2 = (const float*)d_in[8];
    const float* b2 = (const float*)d_in[9];
    float* S  = (float*)d_out;           // 8192x8192 base-2 log_K lives in d_out
    float* ws = (float*)d_ws;
    float* qn     = ws; ws += NR;
    float* kn     = ws; ws += NR;
    float* logb2  = ws; ws += NR;
    float* logits = ws; ws += NR;
    float* f      = ws; ws += NR;
    float* g      = ws; ws += NR;
    float2* pms   = (float2*)ws;         // NBLK * NR float2 = 16 MB
    // q,k (8 MB each) overlay the pms region: dist phase completes before any
    // partial is written, and q/k are dead once dist_kernel finishes.
    float* q = (float*)pms;
    float* k = q + (size_t)NR * DIM;

    const float log_a2 = -13.0f; // log2(1/8192 + 1e-20)

    init_zero<<<32, 256, 0, stream>>>(g);
    gemm_qk<<<dim3(128, 4), 256, 0, stream>>>(A, Wq, bq, q);
    gemm_qk<<<dim3(128, 4), 256, 0, stream>>>(Tk, Wk, bk, k);
    row_norm<<<NR, 64, 0, stream>>>(q, qn);
    row_norm<<<NR, 64, 0, stream>>>(k, kn);
    mlp_logits<<<NR, 128, 0, stream>>>(A, W1, b1, W2, b2, logits);
    softmax_logb<<<1, 1024, 0, stream>>>(logits, logb2);
    dist_kernel<<<dim3(64, 64), 256, 0, stream>>>(q, k, qn, kn, S);
    for (int it = 0; it < 50; ++it) {
        iter_fused<<<NBLK, 512, 0, stream>>>(S, g, logb2, f, pms);
        col_combine<<<32, 256, 0, stream>>>(pms, g, log_a2);
    }
    write_pass<<<NR / 4, 256, 0, stream>>>(S, f, g, S);
}